// Round 6
// baseline (1196.578 us; speedup 1.0000x reference)
//
#include <hip/hip_runtime.h>
#include <math.h>

// HiDAN split-bf16 MFMA pipeline, round 6.
// R6: gate1+gate2+encode fused into ONE K=2048 GEMM (SPLITA staging: A rows are
// [ch | dep] -- k<1024 from ch, k>=1024 from dep; gate_pre lives entirely in
// fp32 accumulators, no gp buffer). Saves 134 MB gp traffic + one dispatch.
// GEMM inner loop unchanged (at the ~1 PF m97-structure issue rate).
// Buffer lifetimes:
//   B0 (NH f32): embH/L -> ht-hi -> chT H/L
//   B1 (NH f32): chH/L -> encH/L (in-place via fused gate epilogue)
//   B2 (NS f32): W1/Wh/Wt splits -> logits f32 -> scores hi/lo -> Wg/Wm1/tw/Wti splits
//   d_out      : ht-lo -> depH/L -> tinf f32 -> final out
// Fallback: round-1 fp32 path if ws_size < need.

#define BSZ 32
#define SLEN 512
#define HD 1024
#define DEMB 1024
#define DTW 64

typedef __attribute__((ext_vector_type(8))) short short8;
typedef __attribute__((ext_vector_type(4))) float f32x4;
typedef unsigned short ushort_t;

__device__ __forceinline__ unsigned short f2bf(float x) {
    unsigned int u = __float_as_uint(x);
    u += 0x7FFFu + ((u >> 16) & 1u);
    return (unsigned short)(u >> 16);
}
__device__ __forceinline__ float bf2f(unsigned short h) {
    return __uint_as_float(((unsigned int)h) << 16);
}

__device__ __forceinline__ void gload16(const void* g, void* l) {
    __builtin_amdgcn_global_load_lds((const __attribute__((address_space(1))) unsigned int*)g,
                                     (__attribute__((address_space(3))) unsigned int*)l,
                                     16, 0, 0);
}

// ---------------- split-bf16 MFMA GEMM ----------------
// C[m][n] = sum_k A[m][k]*B[n][k] (NT; hi/lo bf16 operands, k-contiguous rows)
// SWZ: pair-row XCD swizzle (requires gridDim.y==128, z==1).
// SPLITA: A is a virtual [M][2*ldA] concat: k<ldA from AH/AL, k>=ldA from A2H/A2L.
// EPI: 0 = standard (bias/ACT/MSK/ACC/WF32/WBF16)
//      1 = map2 fusion: f_out[m] += elu(x+bias)*f_tinf[m,n]*f_wm2[n]
//      2 = gate+encode: x=acc+bias; g=sig(x); enc=(g*ch+(1-g)*dep)*mask;
//          ch read from OH/OL (overwritten with enc), dep read from A2H/A2L.
template<int ACT, int MSK, int ACC, int WF32, int WBF16, int SWZ, int EPI, int SPLITA>
__global__ __launch_bounds__(256, 2)
void mgemm(const ushort_t* __restrict__ AH, const ushort_t* __restrict__ AL,
           const ushort_t* __restrict__ A2H, const ushort_t* __restrict__ A2L,
           long long ldA, long long bsA,
           const ushort_t* __restrict__ BH, const ushort_t* __restrict__ BL,
           long long ldB, long long bsB,
           const float* __restrict__ bias, const float* __restrict__ rowmask,
           float* __restrict__ C, long long ldC, long long bsC,
           ushort_t* __restrict__ OH, ushort_t* __restrict__ OL,
           long long ldO, long long bsO,
           int M, int N, int K,
           const float* __restrict__ f_tinf, const float* __restrict__ f_wm2,
           float* __restrict__ f_out)
{
    __shared__ alignas(16) ushort_t sAh[128 * 32];
    __shared__ alignas(16) ushort_t sAl[128 * 32];
    __shared__ alignas(16) ushort_t sBh[128 * 32];
    __shared__ alignas(16) ushort_t sBl[128 * 32];

    long long bz = blockIdx.z;
    int tid = threadIdx.x;
    int wv = tid >> 6, lane = tid & 63;
    int wr = wv >> 1, wc = wv & 1;
    int ln = lane & 15, qd = lane >> 4;

    int bx = blockIdx.x, by = blockIdx.y;
    if (SWZ) {
        // pair-row swizzle: XCD X (= L%8 heuristic) sweeps bx over row 2p, then
        // row 2p+1 (B-panel L2 reuse), pairs strided 16 apart.
        int G = gridDim.x;
        int L = by * G + bx;
        int X = L & 7, S = L >> 3;
        bx = S % G;
        int t = S / G;                       // 0..15 when gridDim.y==128
        by = ((t >> 1) * 8 + X) * 2 + (t & 1);
    }
    long long m0 = (long long)by * 128;
    long long n0 = (long long)bx * 128;

    // staging: wave 0->Ahi, 1->Alo, 2->Bhi, 3->Blo; each 128 rows x 32 bf16
    const ushort_t* gsrc;
    const ushort_t* gsrc2 = nullptr;
    ushort_t* ldst;
    long long gld;
    long long lrow = lane >> 2;
    long long lkof = (lane & 3) * 8;
    if (wv == 0)      { gsrc = AH + bz * bsA + (m0 + lrow) * ldA + lkof; ldst = sAh; gld = ldA;
                        if (SPLITA) gsrc2 = A2H + (m0 + lrow) * ldA + lkof; }
    else if (wv == 1) { gsrc = AL + bz * bsA + (m0 + lrow) * ldA + lkof; ldst = sAl; gld = ldA;
                        if (SPLITA) gsrc2 = A2L + (m0 + lrow) * ldA + lkof; }
    else if (wv == 2) { gsrc = BH + bz * bsB + (n0 + lrow) * ldB + lkof; ldst = sBh; gld = ldB; }
    else              { gsrc = BL + bz * bsB + (n0 + lrow) * ldB + lkof; ldst = sBl; gld = ldB; }

    f32x4 acc[4][4] = {};

    for (int k0 = 0; k0 < K; k0 += 32) {
        const ushort_t* p = gsrc;
        long long kk = k0;
        if (SPLITA && wv < 2 && k0 >= (int)ldA) { p = gsrc2; kk = k0 - ldA; }
        #pragma unroll
        for (int i = 0; i < 8; ++i)
            gload16(p + (long long)(16 * i) * gld + kk, ldst + i * 512);
        __syncthreads();

        short8 fah[4], fal[4], fbh[4], fbl[4];
        #pragma unroll
        for (int i = 0; i < 4; ++i) {
            int ra = (64 * wr + 16 * i + ln) * 32 + qd * 8;
            int rb = (64 * wc + 16 * i + ln) * 32 + qd * 8;
            fah[i] = *(const short8*)&sAh[ra];
            fal[i] = *(const short8*)&sAl[ra];
            fbh[i] = *(const short8*)&sBh[rb];
            fbl[i] = *(const short8*)&sBl[rb];
        }
        #pragma unroll
        for (int i = 0; i < 4; ++i)
            #pragma unroll
            for (int j = 0; j < 4; ++j) {
                acc[i][j] = __builtin_amdgcn_mfma_f32_16x16x32_bf16(fah[i], fbh[j], acc[i][j], 0, 0, 0);
                acc[i][j] = __builtin_amdgcn_mfma_f32_16x16x32_bf16(fah[i], fbl[j], acc[i][j], 0, 0, 0);
                acc[i][j] = __builtin_amdgcn_mfma_f32_16x16x32_bf16(fal[i], fbh[j], acc[i][j], 0, 0, 0);
            }
        __syncthreads();
    }

    if (EPI == 1) {
        // map2 partial: f_out[m] += sum_n elu(x+bias[n]) * tinf[m,n] * wm2[n]
        #pragma unroll
        for (int i = 0; i < 4; ++i) {
            #pragma unroll
            for (int t = 0; t < 4; ++t) {
                long long gm = m0 + 64 * wr + 16 * i + qd * 4 + t;
                float part = 0.f;
                #pragma unroll
                for (int j = 0; j < 4; ++j) {
                    long long gn = n0 + 64 * wc + 16 * j + ln;
                    float x = acc[i][j][t] + bias[gn];
                    x = (x > 0.f) ? x : (expf(x) - 1.f);
                    part += x * f_tinf[gm * (long long)N + gn] * f_wm2[gn];
                }
                part += __shfl_xor(part, 1);
                part += __shfl_xor(part, 2);
                part += __shfl_xor(part, 4);
                part += __shfl_xor(part, 8);
                if (ln == 0) atomicAdd(&f_out[gm], part);
            }
        }
        return;
    }

    if (EPI == 2) {
        // fused gate+encode: acc holds ch@WgTop + dep@WgBot (full K=2048);
        // ch in OH/OL (overwritten with enc), dep in A2H/A2L.
        #pragma unroll
        for (int i = 0; i < 4; ++i) {
            #pragma unroll
            for (int t = 0; t < 4; ++t) {
                long long gm = m0 + 64 * wr + 16 * i + qd * 4 + t;
                float mk = rowmask[gm];
                #pragma unroll
                for (int j = 0; j < 4; ++j) {
                    long long gn = n0 + 64 * wc + 16 * j + ln;
                    float x = acc[i][j][t] + bias[gn];
                    float g = 1.f / (1.f + expf(-x));
                    long long o = gm * ldO + gn;
                    float c = bf2f(OH[o]) + bf2f(OL[o]);
                    float d = bf2f(A2H[o]) + bf2f(A2L[o]);
                    float r = (g * c + (1.f - g) * d) * mk;
                    unsigned short h = f2bf(r);
                    OH[o] = h;
                    OL[o] = f2bf(r - bf2f(h));
                }
            }
        }
        return;
    }

    float* Cb = 0;
    ushort_t *OHb = 0, *OLb = 0;
    if (WF32 || ACC) Cb = C + bz * bsC;
    if (WBF16) { OHb = OH + bz * bsO; OLb = OL + bz * bsO; }

    #pragma unroll
    for (int i = 0; i < 4; ++i) {
        #pragma unroll
        for (int t = 0; t < 4; ++t) {
            long long gm = m0 + 64 * wr + 16 * i + qd * 4 + t;
            float mk = 1.f;
            if (MSK) mk = rowmask[gm];
            #pragma unroll
            for (int j = 0; j < 4; ++j) {
                long long gn = n0 + 64 * wc + 16 * j + ln;
                float x = acc[i][j][t];
                if (bias) x += bias[gn];
                if (ACC) x += Cb[gm * ldC + gn];
                if (ACT) x = (x > 0.f) ? x : (expf(x) - 1.f);
                if (MSK) x *= mk;
                if (WF32 || ACC) Cb[gm * ldC + gn] = x;
                if (WBF16) {
                    unsigned short h = f2bf(x);
                    OHb[gm * ldO + gn] = h;
                    OLb[gm * ldO + gn] = f2bf(x - bf2f(h));
                }
            }
        }
    }
}

// ---------------- helpers ----------------

__global__ __launch_bounds__(256)
void zero_k(float* __restrict__ p, long long n)
{
    long long i = blockIdx.x * 256LL + threadIdx.x;
    if (i < n) p[i] = 0.f;
}

__global__ __launch_bounds__(256)
void split_k(const float* __restrict__ x, ushort_t* __restrict__ h,
             ushort_t* __restrict__ l, long long n4)
{
    long long i = blockIdx.x * 256LL + threadIdx.x;
    long long stride = (long long)gridDim.x * 256LL;
    for (; i < n4; i += stride) {
        float4 v = ((const float4*)x)[i];
        ushort4 hv, lv;
        hv.x = f2bf(v.x); lv.x = f2bf(v.x - bf2f(hv.x));
        hv.y = f2bf(v.y); lv.y = f2bf(v.y - bf2f(hv.y));
        hv.z = f2bf(v.z); lv.z = f2bf(v.z - bf2f(hv.z));
        hv.w = f2bf(v.w); lv.w = f2bf(v.w - bf2f(hv.w));
        ((ushort4*)h)[i] = hv;
        ((ushort4*)l)[i] = lv;
    }
}

// X [K][N] fp32 -> Th/Tl [N][K] bf16 hi/lo
__global__ __launch_bounds__(256)
void tsplit_k(const float* __restrict__ X,
              ushort_t* __restrict__ Th, ushort_t* __restrict__ Tl,
              int K, int N)
{
    __shared__ float t[32][33];
    int n0 = blockIdx.x * 32, k0 = blockIdx.y * 32;
    int tx = threadIdx.x & 31, ty = threadIdx.x >> 5;
    #pragma unroll
    for (int p = 0; p < 32; p += 8)
        t[ty + p][tx] = X[(long long)(k0 + ty + p) * N + n0 + tx];
    __syncthreads();
    #pragma unroll
    for (int p = 0; p < 32; p += 8) {
        float v = t[tx][ty + p];
        unsigned short h = f2bf(v);
        long long o = (long long)(n0 + ty + p) * K + k0 + tx;
        Th[o] = h;
        Tl[o] = f2bf(v - bf2f(h));
    }
}

// batched bf16 hi/lo transpose: [b][R][C] -> [b][C][R]
__global__ __launch_bounds__(256)
void trans_bf_k(const ushort_t* __restrict__ H, const ushort_t* __restrict__ L,
                ushort_t* __restrict__ TH, ushort_t* __restrict__ TL,
                int R, int C)
{
    __shared__ ushort_t sh[32][33];
    __shared__ ushort_t sl[32][33];
    long long b = blockIdx.z;
    long long ib = b * (long long)R * C;
    int c0 = blockIdx.x * 32, r0 = blockIdx.y * 32;
    int tx = threadIdx.x & 31, ty = threadIdx.x >> 5;
    #pragma unroll
    for (int p = 0; p < 32; p += 8) {
        long long src = ib + (long long)(r0 + ty + p) * C + c0 + tx;
        sh[ty + p][tx] = H[src];
        sl[ty + p][tx] = L[src];
    }
    __syncthreads();
    #pragma unroll
    for (int p = 0; p < 32; p += 8) {
        long long dst = ib + (long long)(c0 + ty + p) * R + r0 + tx;
        TH[dst] = sh[tx][ty + p];
        TL[dst] = sl[tx][ty + p];
    }
}

// ---------------- fp32 GEMM (fallback only) ----------------
#define BM 64
#define BN 64
#define BK 16

template<int BT, int ACT, int ACC, int MSK>
__global__ __launch_bounds__(256)
void gemm_k(const float* __restrict__ A, long long sAb,
            const float* __restrict__ B, long long sBb,
            const float* __restrict__ bias,
            const float* __restrict__ rowmask,
            float* __restrict__ C, long long sCb,
            int M, int N, int K)
{
    int bz = blockIdx.z;
    A += (long long)bz * sAb;
    B += (long long)bz * sBb;
    C += (long long)bz * sCb;

    __shared__ float As[BK][BM + 4];
    __shared__ float Bs[BK][BN + 4];

    int tid = threadIdx.x;
    int tx = tid & 15;
    int ty = tid >> 4;
    int m0 = blockIdx.y * BM;
    int n0 = blockIdx.x * BN;

    int lm = tid >> 2;
    int lk = (tid & 3) << 2;
    int bk = tid >> 4;
    int bn = (tid & 15) << 2;

    float acc[4][4] = {};

    for (int k0 = 0; k0 < K; k0 += BK) {
        float4 av = *(const float4*)(A + (long long)(m0 + lm) * K + (k0 + lk));
        As[lk + 0][lm] = av.x;
        As[lk + 1][lm] = av.y;
        As[lk + 2][lm] = av.z;
        As[lk + 3][lm] = av.w;
        if (BT) {
            float4 bv = *(const float4*)(B + (long long)(n0 + lm) * K + (k0 + lk));
            Bs[lk + 0][lm] = bv.x;
            Bs[lk + 1][lm] = bv.y;
            Bs[lk + 2][lm] = bv.z;
            Bs[lk + 3][lm] = bv.w;
        } else {
            float4 bv = *(const float4*)(B + (long long)(k0 + bk) * N + (n0 + bn));
            *(float4*)&Bs[bk][bn] = bv;
        }
        __syncthreads();
        #pragma unroll
        for (int k = 0; k < BK; ++k) {
            float4 a4 = *(const float4*)&As[k][ty << 2];
            float4 b4 = *(const float4*)&Bs[k][tx << 2];
            float aa[4] = {a4.x, a4.y, a4.z, a4.w};
            float bb[4] = {b4.x, b4.y, b4.z, b4.w};
            #pragma unroll
            for (int i = 0; i < 4; ++i)
                #pragma unroll
                for (int j = 0; j < 4; ++j)
                    acc[i][j] = fmaf(aa[i], bb[j], acc[i][j]);
        }
        __syncthreads();
    }

    float bvals[4] = {0.f, 0.f, 0.f, 0.f};
    if (bias) {
        float4 b4 = *(const float4*)(bias + n0 + (tx << 2));
        bvals[0] = b4.x; bvals[1] = b4.y; bvals[2] = b4.z; bvals[3] = b4.w;
    }
    #pragma unroll
    for (int i = 0; i < 4; ++i) {
        int m = m0 + (ty << 2) + i;
        float mk = 1.f;
        if (MSK) mk = rowmask[m];
        float* cp = C + (long long)m * N + n0 + (tx << 2);
        float4 cv = make_float4(0.f, 0.f, 0.f, 0.f);
        if (ACC) cv = *(const float4*)cp;
        float v[4];
        #pragma unroll
        for (int j = 0; j < 4; ++j) {
            float x = acc[i][j] + bvals[j];
            if (ACC) x += (&cv.x)[j];
            if (ACT == 1) x = (x > 0.f) ? x : (expf(x) - 1.f);
            if (MSK) x *= mk;
            v[j] = x;
        }
        *(float4*)cp = make_float4(v[0], v[1], v[2], v[3]);
    }
}

// ---------------- softmax / elementwise ----------------

// masked causal softmax, fp32 in -> bf16 hi/lo IN PLACE.
// row r (2048 B): floats [0,512) -> u16 hi [0,512), u16 lo [512,1024).
__global__ __launch_bounds__(256)
void attn_softmax_bf_k(float* __restrict__ score, const float* __restrict__ mask)
{
    int bi = blockIdx.x;
    int b = bi >> 9;
    int i = bi & (SLEN - 1);
    float* row = score + (long long)bi * SLEN;
    ushort_t* us = (ushort_t*)row;
    const float* mrow = mask + (long long)b * SLEN;
    int tid = threadIdx.x;
    int j0 = tid, j1 = tid + 256;
    __shared__ float red[256];

    bool v0 = (j0 < i) && (mrow[j0] > 0.f);
    bool v1 = (j1 < i) && (mrow[j1] > 0.f);
    float x0 = v0 ? row[j0] : -INFINITY;
    float x1 = v1 ? row[j1] : -INFINITY;

    red[tid] = fmaxf(x0, x1); __syncthreads();
    for (int s = 128; s > 0; s >>= 1) {
        if (tid < s) red[tid] = fmaxf(red[tid], red[tid + s]);
        __syncthreads();
    }
    float m = red[0]; __syncthreads();

    float e0 = v0 ? expf(x0 - m) : 0.f;
    float e1 = v1 ? expf(x1 - m) : 0.f;
    red[tid] = e0 + e1; __syncthreads();
    for (int s = 128; s > 0; s >>= 1) {
        if (tid < s) red[tid] += red[tid + s];
        __syncthreads();
    }
    float sum = red[0];
    float inv = (sum > 0.f) ? (1.f / sum) : 0.f;
    float r0 = e0 * inv, r1 = e1 * inv;
    __syncthreads();   // all float reads done before u16 overwrite
    unsigned short h0 = f2bf(r0), h1 = f2bf(r1);
    us[j0] = h0;       us[512 + j0] = f2bf(r0 - bf2f(h0));
    us[j1] = h1;       us[512 + j1] = f2bf(r1 - bf2f(h1));
}

__global__ __launch_bounds__(256)
void pool_softmax_k(const float* __restrict__ map2, const float* __restrict__ mask,
                    float* __restrict__ a)
{
    int b = blockIdx.x;
    const float* xr = map2 + (long long)b * SLEN;
    const float* mr = mask + (long long)b * SLEN;
    float* ar = a + (long long)b * SLEN;
    int tid = threadIdx.x;
    __shared__ float red[256];

    float lmax = -INFINITY;
    for (int j = tid; j < SLEN; j += 256)
        if (mr[j] > 0.f) lmax = fmaxf(lmax, xr[j]);
    red[tid] = lmax; __syncthreads();
    for (int s = 128; s > 0; s >>= 1) {
        if (tid < s) red[tid] = fmaxf(red[tid], red[tid + s]);
        __syncthreads();
    }
    float m = red[0]; __syncthreads();

    float lsum = 0.f;
    for (int j = tid; j < SLEN; j += 256) {
        float e = (mr[j] > 0.f) ? expf(xr[j] - m) : 0.f;
        ar[j] = e;
        lsum += e;
    }
    red[tid] = lsum; __syncthreads();
    for (int s = 128; s > 0; s >>= 1) {
        if (tid < s) red[tid] += red[tid + s];
        __syncthreads();
    }
    float inv = (red[0] > 0.f) ? (1.f / red[0]) : 0.f;
    for (int j = tid; j < SLEN; j += 256) ar[j] *= inv;
}

__global__ __launch_bounds__(256)
void final_bf_k(const ushort_t* __restrict__ encH, const ushort_t* __restrict__ encL,
                const float* __restrict__ a, float* __restrict__ out, long long n4)
{
    long long i = blockIdx.x * 256LL + threadIdx.x;
    long long stride = (long long)gridDim.x * 256LL;
    for (; i < n4; i += stride) {
        ushort4 h4 = ((const ushort4*)encH)[i];
        ushort4 l4 = ((const ushort4*)encL)[i];
        float av = a[i >> 8];
        float4 r;
        r.x = (bf2f(h4.x) + bf2f(l4.x)) * av;
        r.y = (bf2f(h4.y) + bf2f(l4.y)) * av;
        r.z = (bf2f(h4.z) + bf2f(l4.z)) * av;
        r.w = (bf2f(h4.w) + bf2f(l4.w)) * av;
        ((float4*)out)[i] = r;
    }
}

// fp32-path kernels (fallback only)
__global__ __launch_bounds__(256)
void attn_softmax_k(float* __restrict__ score, const float* __restrict__ mask)
{
    int bi = blockIdx.x;
    int b = bi >> 9;
    int i = bi & (SLEN - 1);
    float* row = score + (long long)bi * SLEN;
    const float* mrow = mask + (long long)b * SLEN;
    int tid = threadIdx.x;
    __shared__ float red[256];

    float lmax = -INFINITY;
    for (int j = tid; j < SLEN; j += 256)
        if (j < i && mrow[j] > 0.f) lmax = fmaxf(lmax, row[j]);
    red[tid] = lmax; __syncthreads();
    for (int s = 128; s > 0; s >>= 1) {
        if (tid < s) red[tid] = fmaxf(red[tid], red[tid + s]);
        __syncthreads();
    }
    float m = red[0]; __syncthreads();

    float lsum = 0.f;
    for (int j = tid; j < SLEN; j += 256) {
        bool valid = (j < i && mrow[j] > 0.f);
        float e = valid ? expf(row[j] - m) : 0.f;
        row[j] = e;
        lsum += e;
    }
    red[tid] = lsum; __syncthreads();
    for (int s = 128; s > 0; s >>= 1) {
        if (tid < s) red[tid] += red[tid + s];
        __syncthreads();
    }
    float sum = red[0];
    float inv = (sum > 0.f) ? (1.f / sum) : 0.f;
    for (int j = tid; j < SLEN; j += 256) row[j] *= inv;
}

__global__ __launch_bounds__(256)
void encode_k(const float* __restrict__ gp, float* __restrict__ ch,
              const float* __restrict__ dep, const float* __restrict__ mask,
              long long n4)
{
    long long i = blockIdx.x * 256LL + threadIdx.x;
    long long stride = (long long)gridDim.x * 256LL;
    for (; i < n4; i += stride) {
        float4 g4 = ((const float4*)gp)[i];
        float4 c4 = ((const float4*)ch)[i];
        float4 d4 = ((const float4*)dep)[i];
        float mk = mask[i >> 8];
        float4 r;
        float g = 1.f / (1.f + expf(-g4.x)); r.x = (g * c4.x + (1.f - g) * d4.x) * mk;
        g = 1.f / (1.f + expf(-g4.y)); r.y = (g * c4.y + (1.f - g) * d4.y) * mk;
        g = 1.f / (1.f + expf(-g4.z)); r.z = (g * c4.z + (1.f - g) * d4.z) * mk;
        g = 1.f / (1.f + expf(-g4.w)); r.w = (g * c4.w + (1.f - g) * d4.w) * mk;
        ((float4*)ch)[i] = r;
    }
}

__global__ __launch_bounds__(256)
void map2_k(const float* __restrict__ map1, const float* __restrict__ tinf,
            const float* __restrict__ Wm2, const float* __restrict__ bm2,
            float* __restrict__ out)
{
    long long r = blockIdx.x;
    const float* p1 = map1 + r * HD;
    const float* p2 = tinf + r * HD;
    int tid = threadIdx.x;
    float s = 0.f;
    for (int h = tid; h < HD; h += 256) s += p1[h] * p2[h] * Wm2[h];
    __shared__ float red[256];
    red[tid] = s; __syncthreads();
    for (int st = 128; st > 0; st >>= 1) {
        if (tid < st) red[tid] += red[tid + st];
        __syncthreads();
    }
    if (tid == 0) out[r] = red[0] + bm2[0];
}

__global__ __launch_bounds__(256)
void final_k(const float* __restrict__ enc, const float* __restrict__ a,
             float* __restrict__ out, long long n4)
{
    long long i = blockIdx.x * 256LL + threadIdx.x;
    long long stride = (long long)gridDim.x * 256LL;
    for (; i < n4; i += stride) {
        float4 e4 = ((const float4*)enc)[i];
        float av = a[i >> 8];
        ((float4*)out)[i] = make_float4(e4.x * av, e4.y * av, e4.z * av, e4.w * av);
    }
}

// ---------------- launch ----------------

extern "C" void kernel_launch(void* const* d_in, const int* in_sizes, int n_in,
                              void* d_out, int out_size, void* d_ws, size_t ws_size,
                              hipStream_t stream)
{
    const float* cas_emb     = (const float*)d_in[0];
    const float* cas_mask    = (const float*)d_in[1];
    const float* time_weight = (const float*)d_in[2];
    const float* W1  = (const float*)d_in[3];
    const float* b1  = (const float*)d_in[4];
    const float* Wh  = (const float*)d_in[5];
    const float* bh  = (const float*)d_in[6];
    const float* Wt  = (const float*)d_in[7];
    const float* bt  = (const float*)d_in[8];
    const float* Wg  = (const float*)d_in[9];
    const float* bg  = (const float*)d_in[10];
    const float* Wm1 = (const float*)d_in[11];
    const float* bm1 = (const float*)d_in[12];
    const float* Wti = (const float*)d_in[13];
    const float* bti = (const float*)d_in[14];
    const float* Wm2 = (const float*)d_in[15];
    const float* bm2 = (const float*)d_in[16];
    float* out = (float*)d_out;

    const long long MR = (long long)BSZ * SLEN;        // 16384
    const long long NH = MR * HD;                      // 16777216
    const long long NS = (long long)BSZ * SLEN * SLEN; // 8388608
    const long long WSZ = (long long)HD * DEMB;        // 1048576 elements

    float* B0 = (float*)d_ws;      // NH floats
    float* B1 = B0 + NH;           // NH floats
    float* B2 = B1 + NH;           // NS floats
    float* m2 = B2 + NS;           // MR
    float* av = m2 + MR;           // MR
    size_t need = (size_t)(2 * NH + NS + 2 * MR) * 4;  // round-1 footprint

    dim3 blk(256);
    const float* nofp = nullptr;
    float* nofpm = nullptr;
    const ushort_t* nus = nullptr;

    if (ws_size >= need) {
        // bf16 views
        ushort_t* embH = (ushort_t*)B0; ushort_t* embL = embH + NH;
        ushort_t* chH  = (ushort_t*)B1; ushort_t* chL  = chH + NH;   // -> enc in place
        ushort_t* htH  = (ushort_t*)B0;          // [MR][2048] head|tail hi
        ushort_t* htL  = (ushort_t*)d_out;       // [MR][2048] head|tail lo
        ushort_t* chTH = (ushort_t*)B0; ushort_t* chTL = chTH + NH;
        ushort_t* depH = (ushort_t*)d_out; ushort_t* depL = depH + NH;
        float* Ssc  = B2;                        // logits fp32
        ushort_t* scB = (ushort_t*)B2;           // row-interleaved hi/lo after softmax
        float* tinf = (float*)d_out;             // tinf fp32
        // phase-1 weight splits in B2 (dead before logits)
        ushort_t* Wb = (ushort_t*)B2;
        ushort_t* W1h = Wb,            * W1l  = Wb + WSZ;
        ushort_t* WHTh = Wb + 2 * WSZ, * WHTl = Wb + 4 * WSZ;  // [2048][1024] stacked Wh;Wt
        // phase-2 (after scores dead; B2 = 16*WSZ ushorts total)
        ushort_t* Wgh  = Wb,            * Wgl  = Wb + 2 * WSZ; // [1024][2048]
        ushort_t* Wm1h = Wb + 4 * WSZ,  * Wm1l = Wb + 5 * WSZ;
        ushort_t* twH  = Wb + 6 * WSZ,  * twL  = Wb + 7 * WSZ; // [MR][64]
        ushort_t* WtiTh = Wb + 8 * WSZ, * WtiTl = WtiTh + (long long)HD * DTW;

        // weight splits phase 1 + emb split
        tsplit_k<<<dim3(HD / 32, DEMB / 32), blk, 0, stream>>>(W1, W1h, W1l, DEMB, HD);
        tsplit_k<<<dim3(HD / 32, HD / 32), blk, 0, stream>>>(Wh, WHTh, WHTl, HD, HD);
        tsplit_k<<<dim3(HD / 32, HD / 32), blk, 0, stream>>>(Wt, WHTh + WSZ, WHTl + WSZ, HD, HD);
        split_k<<<dim3(4096), blk, 0, stream>>>(cas_emb, embH, embL, NH / 4);

        // 1. ch = elu(emb@W1+b1)*mask -> B1 hi/lo
        mgemm<1, 1, 0, 0, 1, 1, 0, 0><<<dim3(8, 128, 1), blk, 0, stream>>>(
            embH, embL, nus, nus, DEMB, 0, W1h, W1l, DEMB, 0, b1, cas_mask,
            nullptr, 0, 0, chH, chL, HD, 0, (int)MR, HD, DEMB, nofp, nofp, nofpm);
        // 2. head|tail = ch@[Wh;Wt] + [bh;bt] -> hi in B0, lo in d_out (N=2048)
        {
            float* biasHT = m2;  // m2 free until the map1-fused phase; 2048 <= MR
            hipMemcpyAsync(biasHT, bh, HD * sizeof(float), hipMemcpyDeviceToDevice, stream);
            hipMemcpyAsync(biasHT + HD, bt, HD * sizeof(float), hipMemcpyDeviceToDevice, stream);
            mgemm<0, 0, 0, 0, 1, 1, 0, 0><<<dim3(16, 128, 1), blk, 0, stream>>>(
                chH, chL, nus, nus, HD, 0, WHTh, WHTl, HD, 0, biasHT, nullptr,
                nullptr, 0, 0, htH, htL, 2048, 0, (int)MR, 2048, HD, nofp, nofp, nofpm);
        }
        // 3. logits[b] = head_b @ tail_b^T -> B2 fp32 (W splits dead)
        mgemm<0, 0, 0, 1, 0, 0, 0, 0><<<dim3(4, 4, 32), blk, 0, stream>>>(
            htH, htL, nus, nus, 2048, SLEN * 2048, htH + 1024, htL + 1024, 2048, SLEN * 2048,
            nullptr, nullptr, Ssc, SLEN, SLEN * SLEN,
            nullptr, nullptr, 0, 0, SLEN, SLEN, HD, nofp, nofp, nofpm);
        // 4. masked softmax fp32 -> bf16 hi/lo in place
        attn_softmax_bf_k<<<dim3(BSZ * SLEN), blk, 0, stream>>>(Ssc, cas_mask);
        // 5. chT: [b][i][h] -> [b][h][i] (ht-hi in B0 dead)
        trans_bf_k<<<dim3(HD / 32, SLEN / 32, BSZ), blk, 0, stream>>>(
            chH, chL, chTH, chTL, SLEN, HD);
        // 6. dep[b] = score_b @ ch_b -> d_out hi/lo (ht-lo dead)
        mgemm<0, 0, 0, 0, 1, 0, 0, 0><<<dim3(8, 4, 32), blk, 0, stream>>>(
            scB, scB + 512, nus, nus, 1024, SLEN * 1024, chTH, chTL, SLEN, HD * SLEN,
            nullptr, nullptr, nullptr, 0, 0,
            depH, depL, HD, SLEN * HD, SLEN, HD, SLEN, nofp, nofp, nofpm);
        // weight splits phase 2 (scores dead)
        tsplit_k<<<dim3(HD / 32, 2048 / 32), blk, 0, stream>>>(Wg, Wgh, Wgl, 2048, HD);
        tsplit_k<<<dim3(HD / 32, HD / 32), blk, 0, stream>>>(Wm1, Wm1h, Wm1l, HD, HD);
        split_k<<<dim3(1024), blk, 0, stream>>>(time_weight, twH, twL, MR * DTW / 4);
        tsplit_k<<<dim3(HD / 32, DTW / 32), blk, 0, stream>>>(Wti, WtiTh, WtiTl, DTW, HD);
        // 7. FUSED gate1+gate2+encode: gate_pre = [ch|dep]@Wg + bg (K=2048, SPLITA);
        //    epilogue: enc = (sig(gate_pre)*ch + (1-sig)*dep)*mask -> B1 in place.
        mgemm<0, 0, 0, 0, 0, 1, 2, 1><<<dim3(8, 128, 1), blk, 0, stream>>>(
            chH, chL, depH, depL, HD, 0, Wgh, Wgl, 2048, 0, bg, cas_mask,
            nullptr, 0, 0, chH, chL, HD, 0, (int)MR, HD, 2048, nofp, nofp, nofpm);
        // 8. tinf = elu(tw@WtiT + bti) -> d_out fp32 (dep dead), MFMA K=64
        mgemm<1, 0, 0, 1, 0, 1, 0, 0><<<dim3(8, 128, 1), blk, 0, stream>>>(
            twH, twL, nus, nus, DTW, 0, WtiTh, WtiTl, DTW, 0, bti, nullptr,
            tinf, HD, 0, nullptr, nullptr, 0, 0, (int)MR, HD, DTW, nofp, nofp, nofpm);
        // 9. m2[r] = sum_h elu(enc@Wm1+bm1)[r,h]*tinf[r,h]*Wm2[h] (bm2 dropped:
        //    pool softmax is shift-invariant)
        zero_k<<<dim3(64), blk, 0, stream>>>(m2, MR);
        mgemm<0, 0, 0, 0, 0, 1, 1, 0><<<dim3(8, 128, 1), blk, 0, stream>>>(
            chH, chL, nus, nus, HD, 0, Wm1h, Wm1l, HD, 0, bm1, nullptr,
            nullptr, 0, 0, nullptr, nullptr, 0, 0, (int)MR, HD, HD,
            tinf, Wm2, m2);
        // 10-11.
        pool_softmax_k<<<dim3(BSZ), blk, 0, stream>>>(m2, cas_mask, av);
        final_bf_k<<<dim3(8192), blk, 0, stream>>>(chH, chL, av, out, NH / 4);
    } else {
        // ---- fp32 fallback (round-1 proven path) ----
        float* S0 = B0;
        float* S1 = B1;
        float* S3 = B2;
        dim3 gBig(HD / BN, (int)(MR / BM), 1);
        gemm_k<0, 1, 0, 1><<<gBig, blk, 0, stream>>>(cas_emb, 0, W1, 0, b1, cas_mask, S0, 0, (int)MR, HD, DEMB);
        gemm_k<0, 0, 0, 0><<<gBig, blk, 0, stream>>>(S0, 0, Wh, 0, bh, nullptr, S1, 0, (int)MR, HD, HD);
        gemm_k<0, 0, 0, 0><<<gBig, blk, 0, stream>>>(S0, 0, Wt, 0, bt, nullptr, out, 0, (int)MR, HD, HD);
        gemm_k<1, 0, 0, 0><<<dim3(SLEN / BN, SLEN / BM, BSZ), blk, 0, stream>>>(
            S1, (long long)SLEN * HD, out, (long long)SLEN * HD, nullptr, nullptr,
            S3, (long long)SLEN * SLEN, SLEN, SLEN, HD);
        attn_softmax_k<<<dim3(BSZ * SLEN), blk, 0, stream>>>(S3, cas_mask);
        gemm_k<0, 0, 0, 0><<<dim3(HD / BN, SLEN / BM, BSZ), blk, 0, stream>>>(
            S3, (long long)SLEN * SLEN, S0, (long long)SLEN * HD, nullptr, nullptr,
            out, (long long)SLEN * HD, SLEN, HD, SLEN);
        gemm_k<0, 0, 0, 0><<<gBig, blk, 0, stream>>>(S0, 0, Wg, 0, bg, nullptr, S1, 0, (int)MR, HD, HD);
        gemm_k<0, 0, 1, 0><<<gBig, blk, 0, stream>>>(out, 0, Wg + (long long)HD * HD, 0, nullptr, nullptr, S1, 0, (int)MR, HD, HD);
        long long n4 = NH / 4;
        encode_k<<<dim3(8192), blk, 0, stream>>>(S1, S0, out, cas_mask, n4);
        gemm_k<0, 1, 0, 0><<<gBig, blk, 0, stream>>>(S0, 0, Wm1, 0, bm1, nullptr, S1, 0, (int)MR, HD, HD);
        gemm_k<0, 1, 0, 0><<<gBig, blk, 0, stream>>>(time_weight, 0, Wti, 0, bti, nullptr, out, 0, (int)MR, HD, DTW);
        map2_k<<<dim3((int)MR), blk, 0, stream>>>(S1, out, Wm2, bm2, m2);
        pool_softmax_k<<<dim3(BSZ), blk, 0, stream>>>(m2, cas_mask, av);
        final_k<<<dim3(8192), blk, 0, stream>>>(S0, av, out, n4);
    }
}

// Round 7
// 1106.654 us; speedup vs baseline: 1.0813x; 1.0813x over previous
//
#include <hip/hip_runtime.h>
#include <math.h>

// HiDAN split-bf16 MFMA pipeline, round 7 == round 5 revert.
// R6 FAILED post-mortem: fusing gate1+gate2 (K=2048, SPLITA) raised VGPR 64->80,
// dropped occupancy 38%->23% (3->2 blocks/CU cliff), fused kernel 309us vs the
// R5 pair's ~242us. Reverted to R5's proven sequence (1129us):
//   gate1 (EPI=0, gp fp32) + gate2 (EPI=2 gate+encode, in-place enc).
// Buffer lifetimes:
//   B0 (NH f32): embH/L -> ht-hi -> chT H/L -> gate_pre f32
//   B1 (NH f32): chH/L -> encH/L (in-place via gate2 epilogue)
//   B2 (NS f32): W1/Wh/Wt splits -> logits f32 -> scores hi/lo -> Wg/Wm1/tw/Wti splits
//   d_out      : ht-lo -> depH/L -> tinf f32 -> final out
// Fallback: round-1 fp32 path if ws_size < need.

#define BSZ 32
#define SLEN 512
#define HD 1024
#define DEMB 1024
#define DTW 64

typedef __attribute__((ext_vector_type(8))) short short8;
typedef __attribute__((ext_vector_type(4))) float f32x4;
typedef unsigned short ushort_t;

__device__ __forceinline__ unsigned short f2bf(float x) {
    unsigned int u = __float_as_uint(x);
    u += 0x7FFFu + ((u >> 16) & 1u);
    return (unsigned short)(u >> 16);
}
__device__ __forceinline__ float bf2f(unsigned short h) {
    return __uint_as_float(((unsigned int)h) << 16);
}

__device__ __forceinline__ void gload16(const void* g, void* l) {
    __builtin_amdgcn_global_load_lds((const __attribute__((address_space(1))) unsigned int*)g,
                                     (__attribute__((address_space(3))) unsigned int*)l,
                                     16, 0, 0);
}

// ---------------- split-bf16 MFMA GEMM ----------------
// C[m][n] = sum_k A[m][k]*B[n][k] (NT; hi/lo bf16 operands, k-contiguous rows)
// SWZ: pair-row XCD swizzle (requires gridDim.y==128, z==1).
// EPI: 0 = standard (bias/ACT/MSK/ACC/WF32/WBF16)
//      1 = map2 fusion: f_out[m] += elu(x+bias)*f_tinf[m,n]*f_wm2[n]
//      2 = gate+encode: x=acc+C (gp); g=sig(x); enc=(g*ch+(1-g)*dep)*mask;
//          ch read from OH/OL (overwritten with enc), dep read from AH/AL.
template<int ACT, int MSK, int ACC, int WF32, int WBF16, int SWZ, int EPI>
__global__ __launch_bounds__(256, 2)
void mgemm(const ushort_t* __restrict__ AH, const ushort_t* __restrict__ AL,
           long long ldA, long long bsA,
           const ushort_t* __restrict__ BH, const ushort_t* __restrict__ BL,
           long long ldB, long long bsB,
           const float* __restrict__ bias, const float* __restrict__ rowmask,
           float* __restrict__ C, long long ldC, long long bsC,
           ushort_t* __restrict__ OH, ushort_t* __restrict__ OL,
           long long ldO, long long bsO,
           int M, int N, int K,
           const float* __restrict__ f_tinf, const float* __restrict__ f_wm2,
           float* __restrict__ f_out)
{
    __shared__ alignas(16) ushort_t sAh[128 * 32];
    __shared__ alignas(16) ushort_t sAl[128 * 32];
    __shared__ alignas(16) ushort_t sBh[128 * 32];
    __shared__ alignas(16) ushort_t sBl[128 * 32];

    long long bz = blockIdx.z;
    int tid = threadIdx.x;
    int wv = tid >> 6, lane = tid & 63;
    int wr = wv >> 1, wc = wv & 1;
    int ln = lane & 15, qd = lane >> 4;

    int bx = blockIdx.x, by = blockIdx.y;
    if (SWZ) {
        // pair-row swizzle: XCD X (= L%8 heuristic) sweeps bx over row 2p, then
        // row 2p+1 (B-panel L2 reuse), pairs strided 16 apart.
        int G = gridDim.x;
        int L = by * G + bx;
        int X = L & 7, S = L >> 3;
        bx = S % G;
        int t = S / G;                       // 0..15 when gridDim.y==128
        by = ((t >> 1) * 8 + X) * 2 + (t & 1);
    }
    long long m0 = (long long)by * 128;
    long long n0 = (long long)bx * 128;

    // staging: wave 0->Ahi, 1->Alo, 2->Bhi, 3->Blo; each 128 rows x 32 bf16
    const ushort_t* gsrc;
    ushort_t* ldst;
    long long gld;
    if (wv == 0)      { gsrc = AH + bz * bsA + (m0 + (lane >> 2)) * ldA; ldst = sAh; gld = ldA; }
    else if (wv == 1) { gsrc = AL + bz * bsA + (m0 + (lane >> 2)) * ldA; ldst = sAl; gld = ldA; }
    else if (wv == 2) { gsrc = BH + bz * bsB + (n0 + (lane >> 2)) * ldB; ldst = sBh; gld = ldB; }
    else              { gsrc = BL + bz * bsB + (n0 + (lane >> 2)) * ldB; ldst = sBl; gld = ldB; }
    gsrc += (lane & 3) * 8;

    f32x4 acc[4][4] = {};

    for (int k0 = 0; k0 < K; k0 += 32) {
        #pragma unroll
        for (int i = 0; i < 8; ++i)
            gload16(gsrc + (long long)(16 * i) * gld + k0, ldst + i * 512);
        __syncthreads();

        short8 fah[4], fal[4], fbh[4], fbl[4];
        #pragma unroll
        for (int i = 0; i < 4; ++i) {
            int ra = (64 * wr + 16 * i + ln) * 32 + qd * 8;
            int rb = (64 * wc + 16 * i + ln) * 32 + qd * 8;
            fah[i] = *(const short8*)&sAh[ra];
            fal[i] = *(const short8*)&sAl[ra];
            fbh[i] = *(const short8*)&sBh[rb];
            fbl[i] = *(const short8*)&sBl[rb];
        }
        #pragma unroll
        for (int i = 0; i < 4; ++i)
            #pragma unroll
            for (int j = 0; j < 4; ++j) {
                acc[i][j] = __builtin_amdgcn_mfma_f32_16x16x32_bf16(fah[i], fbh[j], acc[i][j], 0, 0, 0);
                acc[i][j] = __builtin_amdgcn_mfma_f32_16x16x32_bf16(fah[i], fbl[j], acc[i][j], 0, 0, 0);
                acc[i][j] = __builtin_amdgcn_mfma_f32_16x16x32_bf16(fal[i], fbh[j], acc[i][j], 0, 0, 0);
            }
        __syncthreads();
    }

    if (EPI == 1) {
        // map2 partial: f_out[m] += sum_n elu(x+bias[n]) * tinf[m,n] * wm2[n]
        #pragma unroll
        for (int i = 0; i < 4; ++i) {
            #pragma unroll
            for (int t = 0; t < 4; ++t) {
                long long gm = m0 + 64 * wr + 16 * i + qd * 4 + t;
                float part = 0.f;
                #pragma unroll
                for (int j = 0; j < 4; ++j) {
                    long long gn = n0 + 64 * wc + 16 * j + ln;
                    float x = acc[i][j][t] + bias[gn];
                    x = (x > 0.f) ? x : (expf(x) - 1.f);
                    part += x * f_tinf[gm * (long long)N + gn] * f_wm2[gn];
                }
                part += __shfl_xor(part, 1);
                part += __shfl_xor(part, 2);
                part += __shfl_xor(part, 4);
                part += __shfl_xor(part, 8);
                if (ln == 0) atomicAdd(&f_out[gm], part);
            }
        }
        return;
    }

    if (EPI == 2) {
        // gate2 + encode: A was dep, OH/OL hold ch (overwritten with enc)
        #pragma unroll
        for (int i = 0; i < 4; ++i) {
            #pragma unroll
            for (int t = 0; t < 4; ++t) {
                long long gm = m0 + 64 * wr + 16 * i + qd * 4 + t;
                float mk = rowmask[gm];
                #pragma unroll
                for (int j = 0; j < 4; ++j) {
                    long long gn = n0 + 64 * wc + 16 * j + ln;
                    float x = acc[i][j][t] + C[gm * ldC + gn];   // + gp (WgTop pass)
                    float g = 1.f / (1.f + expf(-x));
                    long long o = gm * ldO + gn;
                    float c = bf2f(OH[o]) + bf2f(OL[o]);
                    long long ai = gm * ldA + gn;
                    float d = bf2f(AH[ai]) + bf2f(AL[ai]);
                    float r = (g * c + (1.f - g) * d) * mk;
                    unsigned short h = f2bf(r);
                    OH[o] = h;
                    OL[o] = f2bf(r - bf2f(h));
                }
            }
        }
        return;
    }

    float* Cb = 0;
    ushort_t *OHb = 0, *OLb = 0;
    if (WF32 || ACC) Cb = C + bz * bsC;
    if (WBF16) { OHb = OH + bz * bsO; OLb = OL + bz * bsO; }

    #pragma unroll
    for (int i = 0; i < 4; ++i) {
        #pragma unroll
        for (int t = 0; t < 4; ++t) {
            long long gm = m0 + 64 * wr + 16 * i + qd * 4 + t;
            float mk = 1.f;
            if (MSK) mk = rowmask[gm];
            #pragma unroll
            for (int j = 0; j < 4; ++j) {
                long long gn = n0 + 64 * wc + 16 * j + ln;
                float x = acc[i][j][t];
                if (bias) x += bias[gn];
                if (ACC) x += Cb[gm * ldC + gn];
                if (ACT) x = (x > 0.f) ? x : (expf(x) - 1.f);
                if (MSK) x *= mk;
                if (WF32 || ACC) Cb[gm * ldC + gn] = x;
                if (WBF16) {
                    unsigned short h = f2bf(x);
                    OHb[gm * ldO + gn] = h;
                    OLb[gm * ldO + gn] = f2bf(x - bf2f(h));
                }
            }
        }
    }
}

// ---------------- helpers ----------------

__global__ __launch_bounds__(256)
void zero_k(float* __restrict__ p, long long n)
{
    long long i = blockIdx.x * 256LL + threadIdx.x;
    if (i < n) p[i] = 0.f;
}

__global__ __launch_bounds__(256)
void split_k(const float* __restrict__ x, ushort_t* __restrict__ h,
             ushort_t* __restrict__ l, long long n4)
{
    long long i = blockIdx.x * 256LL + threadIdx.x;
    long long stride = (long long)gridDim.x * 256LL;
    for (; i < n4; i += stride) {
        float4 v = ((const float4*)x)[i];
        ushort4 hv, lv;
        hv.x = f2bf(v.x); lv.x = f2bf(v.x - bf2f(hv.x));
        hv.y = f2bf(v.y); lv.y = f2bf(v.y - bf2f(hv.y));
        hv.z = f2bf(v.z); lv.z = f2bf(v.z - bf2f(hv.z));
        hv.w = f2bf(v.w); lv.w = f2bf(v.w - bf2f(hv.w));
        ((ushort4*)h)[i] = hv;
        ((ushort4*)l)[i] = lv;
    }
}

// X [K][N] fp32 -> Th/Tl [N][K] bf16 hi/lo
__global__ __launch_bounds__(256)
void tsplit_k(const float* __restrict__ X,
              ushort_t* __restrict__ Th, ushort_t* __restrict__ Tl,
              int K, int N)
{
    __shared__ float t[32][33];
    int n0 = blockIdx.x * 32, k0 = blockIdx.y * 32;
    int tx = threadIdx.x & 31, ty = threadIdx.x >> 5;
    #pragma unroll
    for (int p = 0; p < 32; p += 8)
        t[ty + p][tx] = X[(long long)(k0 + ty + p) * N + n0 + tx];
    __syncthreads();
    #pragma unroll
    for (int p = 0; p < 32; p += 8) {
        float v = t[tx][ty + p];
        unsigned short h = f2bf(v);
        long long o = (long long)(n0 + ty + p) * K + k0 + tx;
        Th[o] = h;
        Tl[o] = f2bf(v - bf2f(h));
    }
}

// batched bf16 hi/lo transpose: [b][R][C] -> [b][C][R]
__global__ __launch_bounds__(256)
void trans_bf_k(const ushort_t* __restrict__ H, const ushort_t* __restrict__ L,
                ushort_t* __restrict__ TH, ushort_t* __restrict__ TL,
                int R, int C)
{
    __shared__ ushort_t sh[32][33];
    __shared__ ushort_t sl[32][33];
    long long b = blockIdx.z;
    long long ib = b * (long long)R * C;
    int c0 = blockIdx.x * 32, r0 = blockIdx.y * 32;
    int tx = threadIdx.x & 31, ty = threadIdx.x >> 5;
    #pragma unroll
    for (int p = 0; p < 32; p += 8) {
        long long src = ib + (long long)(r0 + ty + p) * C + c0 + tx;
        sh[ty + p][tx] = H[src];
        sl[ty + p][tx] = L[src];
    }
    __syncthreads();
    #pragma unroll
    for (int p = 0; p < 32; p += 8) {
        long long dst = ib + (long long)(c0 + ty + p) * R + r0 + tx;
        TH[dst] = sh[tx][ty + p];
        TL[dst] = sl[tx][ty + p];
    }
}

// ---------------- fp32 GEMM (fallback only) ----------------
#define BM 64
#define BN 64
#define BK 16

template<int BT, int ACT, int ACC, int MSK>
__global__ __launch_bounds__(256)
void gemm_k(const float* __restrict__ A, long long sAb,
            const float* __restrict__ B, long long sBb,
            const float* __restrict__ bias,
            const float* __restrict__ rowmask,
            float* __restrict__ C, long long sCb,
            int M, int N, int K)
{
    int bz = blockIdx.z;
    A += (long long)bz * sAb;
    B += (long long)bz * sBb;
    C += (long long)bz * sCb;

    __shared__ float As[BK][BM + 4];
    __shared__ float Bs[BK][BN + 4];

    int tid = threadIdx.x;
    int tx = tid & 15;
    int ty = tid >> 4;
    int m0 = blockIdx.y * BM;
    int n0 = blockIdx.x * BN;

    int lm = tid >> 2;
    int lk = (tid & 3) << 2;
    int bk = tid >> 4;
    int bn = (tid & 15) << 2;

    float acc[4][4] = {};

    for (int k0 = 0; k0 < K; k0 += BK) {
        float4 av = *(const float4*)(A + (long long)(m0 + lm) * K + (k0 + lk));
        As[lk + 0][lm] = av.x;
        As[lk + 1][lm] = av.y;
        As[lk + 2][lm] = av.z;
        As[lk + 3][lm] = av.w;
        if (BT) {
            float4 bv = *(const float4*)(B + (long long)(n0 + lm) * K + (k0 + lk));
            Bs[lk + 0][lm] = bv.x;
            Bs[lk + 1][lm] = bv.y;
            Bs[lk + 2][lm] = bv.z;
            Bs[lk + 3][lm] = bv.w;
        } else {
            float4 bv = *(const float4*)(B + (long long)(k0 + bk) * N + (n0 + bn));
            *(float4*)&Bs[bk][bn] = bv;
        }
        __syncthreads();
        #pragma unroll
        for (int k = 0; k < BK; ++k) {
            float4 a4 = *(const float4*)&As[k][ty << 2];
            float4 b4 = *(const float4*)&Bs[k][tx << 2];
            float aa[4] = {a4.x, a4.y, a4.z, a4.w};
            float bb[4] = {b4.x, b4.y, b4.z, b4.w};
            #pragma unroll
            for (int i = 0; i < 4; ++i)
                #pragma unroll
                for (int j = 0; j < 4; ++j)
                    acc[i][j] = fmaf(aa[i], bb[j], acc[i][j]);
        }
        __syncthreads();
    }

    float bvals[4] = {0.f, 0.f, 0.f, 0.f};
    if (bias) {
        float4 b4 = *(const float4*)(bias + n0 + (tx << 2));
        bvals[0] = b4.x; bvals[1] = b4.y; bvals[2] = b4.z; bvals[3] = b4.w;
    }
    #pragma unroll
    for (int i = 0; i < 4; ++i) {
        int m = m0 + (ty << 2) + i;
        float mk = 1.f;
        if (MSK) mk = rowmask[m];
        float* cp = C + (long long)m * N + n0 + (tx << 2);
        float4 cv = make_float4(0.f, 0.f, 0.f, 0.f);
        if (ACC) cv = *(const float4*)cp;
        float v[4];
        #pragma unroll
        for (int j = 0; j < 4; ++j) {
            float x = acc[i][j] + bvals[j];
            if (ACC) x += (&cv.x)[j];
            if (ACT == 1) x = (x > 0.f) ? x : (expf(x) - 1.f);
            if (MSK) x *= mk;
            v[j] = x;
        }
        *(float4*)cp = make_float4(v[0], v[1], v[2], v[3]);
    }
}

// ---------------- softmax / elementwise ----------------

// masked causal softmax, fp32 in -> bf16 hi/lo IN PLACE.
// row r (2048 B): floats [0,512) -> u16 hi [0,512), u16 lo [512,1024).
__global__ __launch_bounds__(256)
void attn_softmax_bf_k(float* __restrict__ score, const float* __restrict__ mask)
{
    int bi = blockIdx.x;
    int b = bi >> 9;
    int i = bi & (SLEN - 1);
    float* row = score + (long long)bi * SLEN;
    ushort_t* us = (ushort_t*)row;
    const float* mrow = mask + (long long)b * SLEN;
    int tid = threadIdx.x;
    int j0 = tid, j1 = tid + 256;
    __shared__ float red[256];

    bool v0 = (j0 < i) && (mrow[j0] > 0.f);
    bool v1 = (j1 < i) && (mrow[j1] > 0.f);
    float x0 = v0 ? row[j0] : -INFINITY;
    float x1 = v1 ? row[j1] : -INFINITY;

    red[tid] = fmaxf(x0, x1); __syncthreads();
    for (int s = 128; s > 0; s >>= 1) {
        if (tid < s) red[tid] = fmaxf(red[tid], red[tid + s]);
        __syncthreads();
    }
    float m = red[0]; __syncthreads();

    float e0 = v0 ? expf(x0 - m) : 0.f;
    float e1 = v1 ? expf(x1 - m) : 0.f;
    red[tid] = e0 + e1; __syncthreads();
    for (int s = 128; s > 0; s >>= 1) {
        if (tid < s) red[tid] += red[tid + s];
        __syncthreads();
    }
    float sum = red[0];
    float inv = (sum > 0.f) ? (1.f / sum) : 0.f;
    float r0 = e0 * inv, r1 = e1 * inv;
    __syncthreads();   // all float reads done before u16 overwrite
    unsigned short h0 = f2bf(r0), h1 = f2bf(r1);
    us[j0] = h0;       us[512 + j0] = f2bf(r0 - bf2f(h0));
    us[j1] = h1;       us[512 + j1] = f2bf(r1 - bf2f(h1));
}

__global__ __launch_bounds__(256)
void pool_softmax_k(const float* __restrict__ map2, const float* __restrict__ mask,
                    float* __restrict__ a)
{
    int b = blockIdx.x;
    const float* xr = map2 + (long long)b * SLEN;
    const float* mr = mask + (long long)b * SLEN;
    float* ar = a + (long long)b * SLEN;
    int tid = threadIdx.x;
    __shared__ float red[256];

    float lmax = -INFINITY;
    for (int j = tid; j < SLEN; j += 256)
        if (mr[j] > 0.f) lmax = fmaxf(lmax, xr[j]);
    red[tid] = lmax; __syncthreads();
    for (int s = 128; s > 0; s >>= 1) {
        if (tid < s) red[tid] = fmaxf(red[tid], red[tid + s]);
        __syncthreads();
    }
    float m = red[0]; __syncthreads();

    float lsum = 0.f;
    for (int j = tid; j < SLEN; j += 256) {
        float e = (mr[j] > 0.f) ? expf(xr[j] - m) : 0.f;
        ar[j] = e;
        lsum += e;
    }
    red[tid] = lsum; __syncthreads();
    for (int s = 128; s > 0; s >>= 1) {
        if (tid < s) red[tid] += red[tid + s];
        __syncthreads();
    }
    float inv = (red[0] > 0.f) ? (1.f / red[0]) : 0.f;
    for (int j = tid; j < SLEN; j += 256) ar[j] *= inv;
}

__global__ __launch_bounds__(256)
void final_bf_k(const ushort_t* __restrict__ encH, const ushort_t* __restrict__ encL,
                const float* __restrict__ a, float* __restrict__ out, long long n4)
{
    long long i = blockIdx.x * 256LL + threadIdx.x;
    long long stride = (long long)gridDim.x * 256LL;
    for (; i < n4; i += stride) {
        ushort4 h4 = ((const ushort4*)encH)[i];
        ushort4 l4 = ((const ushort4*)encL)[i];
        float av = a[i >> 8];
        float4 r;
        r.x = (bf2f(h4.x) + bf2f(l4.x)) * av;
        r.y = (bf2f(h4.y) + bf2f(l4.y)) * av;
        r.z = (bf2f(h4.z) + bf2f(l4.z)) * av;
        r.w = (bf2f(h4.w) + bf2f(l4.w)) * av;
        ((float4*)out)[i] = r;
    }
}

// fp32-path kernels (fallback only)
__global__ __launch_bounds__(256)
void attn_softmax_k(float* __restrict__ score, const float* __restrict__ mask)
{
    int bi = blockIdx.x;
    int b = bi >> 9;
    int i = bi & (SLEN - 1);
    float* row = score + (long long)bi * SLEN;
    const float* mrow = mask + (long long)b * SLEN;
    int tid = threadIdx.x;
    __shared__ float red[256];

    float lmax = -INFINITY;
    for (int j = tid; j < SLEN; j += 256)
        if (j < i && mrow[j] > 0.f) lmax = fmaxf(lmax, row[j]);
    red[tid] = lmax; __syncthreads();
    for (int s = 128; s > 0; s >>= 1) {
        if (tid < s) red[tid] = fmaxf(red[tid], red[tid + s]);
        __syncthreads();
    }
    float m = red[0]; __syncthreads();

    float lsum = 0.f;
    for (int j = tid; j < SLEN; j += 256) {
        bool valid = (j < i && mrow[j] > 0.f);
        float e = valid ? expf(row[j] - m) : 0.f;
        row[j] = e;
        lsum += e;
    }
    red[tid] = lsum; __syncthreads();
    for (int s = 128; s > 0; s >>= 1) {
        if (tid < s) red[tid] += red[tid + s];
        __syncthreads();
    }
    float sum = red[0];
    float inv = (sum > 0.f) ? (1.f / sum) : 0.f;
    for (int j = tid; j < SLEN; j += 256) row[j] *= inv;
}

__global__ __launch_bounds__(256)
void encode_k(const float* __restrict__ gp, float* __restrict__ ch,
              const float* __restrict__ dep, const float* __restrict__ mask,
              long long n4)
{
    long long i = blockIdx.x * 256LL + threadIdx.x;
    long long stride = (long long)gridDim.x * 256LL;
    for (; i < n4; i += stride) {
        float4 g4 = ((const float4*)gp)[i];
        float4 c4 = ((const float4*)ch)[i];
        float4 d4 = ((const float4*)dep)[i];
        float mk = mask[i >> 8];
        float4 r;
        float g = 1.f / (1.f + expf(-g4.x)); r.x = (g * c4.x + (1.f - g) * d4.x) * mk;
        g = 1.f / (1.f + expf(-g4.y)); r.y = (g * c4.y + (1.f - g) * d4.y) * mk;
        g = 1.f / (1.f + expf(-g4.z)); r.z = (g * c4.z + (1.f - g) * d4.z) * mk;
        g = 1.f / (1.f + expf(-g4.w)); r.w = (g * c4.w + (1.f - g) * d4.w) * mk;
        ((float4*)ch)[i] = r;
    }
}

__global__ __launch_bounds__(256)
void map2_k(const float* __restrict__ map1, const float* __restrict__ tinf,
            const float* __restrict__ Wm2, const float* __restrict__ bm2,
            float* __restrict__ out)
{
    long long r = blockIdx.x;
    const float* p1 = map1 + r * HD;
    const float* p2 = tinf + r * HD;
    int tid = threadIdx.x;
    float s = 0.f;
    for (int h = tid; h < HD; h += 256) s += p1[h] * p2[h] * Wm2[h];
    __shared__ float red[256];
    red[tid] = s; __syncthreads();
    for (int st = 128; st > 0; st >>= 1) {
        if (tid < st) red[tid] += red[tid + st];
        __syncthreads();
    }
    if (tid == 0) out[r] = red[0] + bm2[0];
}

__global__ __launch_bounds__(256)
void final_k(const float* __restrict__ enc, const float* __restrict__ a,
             float* __restrict__ out, long long n4)
{
    long long i = blockIdx.x * 256LL + threadIdx.x;
    long long stride = (long long)gridDim.x * 256LL;
    for (; i < n4; i += stride) {
        float4 e4 = ((const float4*)enc)[i];
        float av = a[i >> 8];
        ((float4*)out)[i] = make_float4(e4.x * av, e4.y * av, e4.z * av, e4.w * av);
    }
}

// ---------------- launch ----------------

extern "C" void kernel_launch(void* const* d_in, const int* in_sizes, int n_in,
                              void* d_out, int out_size, void* d_ws, size_t ws_size,
                              hipStream_t stream)
{
    const float* cas_emb     = (const float*)d_in[0];
    const float* cas_mask    = (const float*)d_in[1];
    const float* time_weight = (const float*)d_in[2];
    const float* W1  = (const float*)d_in[3];
    const float* b1  = (const float*)d_in[4];
    const float* Wh  = (const float*)d_in[5];
    const float* bh  = (const float*)d_in[6];
    const float* Wt  = (const float*)d_in[7];
    const float* bt  = (const float*)d_in[8];
    const float* Wg  = (const float*)d_in[9];
    const float* bg  = (const float*)d_in[10];
    const float* Wm1 = (const float*)d_in[11];
    const float* bm1 = (const float*)d_in[12];
    const float* Wti = (const float*)d_in[13];
    const float* bti = (const float*)d_in[14];
    const float* Wm2 = (const float*)d_in[15];
    const float* bm2 = (const float*)d_in[16];
    float* out = (float*)d_out;

    const long long MR = (long long)BSZ * SLEN;        // 16384
    const long long NH = MR * HD;                      // 16777216
    const long long NS = (long long)BSZ * SLEN * SLEN; // 8388608
    const long long WSZ = (long long)HD * DEMB;        // 1048576 elements

    float* B0 = (float*)d_ws;      // NH floats
    float* B1 = B0 + NH;           // NH floats
    float* B2 = B1 + NH;           // NS floats
    float* m2 = B2 + NS;           // MR
    float* av = m2 + MR;           // MR
    size_t need = (size_t)(2 * NH + NS + 2 * MR) * 4;  // round-1 footprint

    dim3 blk(256);
    const float* nofp = nullptr;
    float* nofpm = nullptr;

    if (ws_size >= need) {
        // bf16 views
        ushort_t* embH = (ushort_t*)B0; ushort_t* embL = embH + NH;
        ushort_t* chH  = (ushort_t*)B1; ushort_t* chL  = chH + NH;   // -> enc in place
        ushort_t* htH  = (ushort_t*)B0;          // [MR][2048] head|tail hi
        ushort_t* htL  = (ushort_t*)d_out;       // [MR][2048] head|tail lo
        ushort_t* chTH = (ushort_t*)B0; ushort_t* chTL = chTH + NH;
        ushort_t* depH = (ushort_t*)d_out; ushort_t* depL = depH + NH;
        float* Ssc  = B2;                        // logits fp32
        ushort_t* scB = (ushort_t*)B2;           // row-interleaved hi/lo after softmax
        float* gp   = B0;                        // gate_pre fp32
        float* tinf = (float*)d_out;             // tinf fp32
        // phase-1 weight splits in B2 (dead before logits)
        ushort_t* Wb = (ushort_t*)B2;
        ushort_t* W1h = Wb,            * W1l  = Wb + WSZ;
        ushort_t* WHTh = Wb + 2 * WSZ, * WHTl = Wb + 4 * WSZ;  // [2048][1024] stacked Wh;Wt
        // phase-2 (after scores dead; B2 = 16*WSZ ushorts total)
        ushort_t* Wgh  = Wb,            * Wgl  = Wb + 2 * WSZ; // [1024][2048]
        ushort_t* Wm1h = Wb + 4 * WSZ,  * Wm1l = Wb + 5 * WSZ;
        ushort_t* twH  = Wb + 6 * WSZ,  * twL  = Wb + 7 * WSZ; // [MR][64]
        ushort_t* WtiTh = Wb + 8 * WSZ, * WtiTl = WtiTh + (long long)HD * DTW;

        // weight splits phase 1 + emb split
        tsplit_k<<<dim3(HD / 32, DEMB / 32), blk, 0, stream>>>(W1, W1h, W1l, DEMB, HD);
        tsplit_k<<<dim3(HD / 32, HD / 32), blk, 0, stream>>>(Wh, WHTh, WHTl, HD, HD);
        tsplit_k<<<dim3(HD / 32, HD / 32), blk, 0, stream>>>(Wt, WHTh + WSZ, WHTl + WSZ, HD, HD);
        split_k<<<dim3(4096), blk, 0, stream>>>(cas_emb, embH, embL, NH / 4);

        // 1. ch = elu(emb@W1+b1)*mask -> B1 hi/lo
        mgemm<1, 1, 0, 0, 1, 1, 0><<<dim3(8, 128, 1), blk, 0, stream>>>(
            embH, embL, DEMB, 0, W1h, W1l, DEMB, 0, b1, cas_mask,
            nullptr, 0, 0, chH, chL, HD, 0, (int)MR, HD, DEMB, nofp, nofp, nofpm);
        // 2. head|tail = ch@[Wh;Wt] + [bh;bt] -> hi in B0, lo in d_out (N=2048)
        {
            float* biasHT = m2;  // m2 free until the map1-fused phase; 2048 <= MR
            hipMemcpyAsync(biasHT, bh, HD * sizeof(float), hipMemcpyDeviceToDevice, stream);
            hipMemcpyAsync(biasHT + HD, bt, HD * sizeof(float), hipMemcpyDeviceToDevice, stream);
            mgemm<0, 0, 0, 0, 1, 1, 0><<<dim3(16, 128, 1), blk, 0, stream>>>(
                chH, chL, HD, 0, WHTh, WHTl, HD, 0, biasHT, nullptr,
                nullptr, 0, 0, htH, htL, 2048, 0, (int)MR, 2048, HD, nofp, nofp, nofpm);
        }
        // 3. logits[b] = head_b @ tail_b^T -> B2 fp32 (W splits dead)
        mgemm<0, 0, 0, 1, 0, 0, 0><<<dim3(4, 4, 32), blk, 0, stream>>>(
            htH, htL, 2048, SLEN * 2048, htH + 1024, htL + 1024, 2048, SLEN * 2048,
            nullptr, nullptr, Ssc, SLEN, SLEN * SLEN,
            nullptr, nullptr, 0, 0, SLEN, SLEN, HD, nofp, nofp, nofpm);
        // 4. masked softmax fp32 -> bf16 hi/lo in place
        attn_softmax_bf_k<<<dim3(BSZ * SLEN), blk, 0, stream>>>(Ssc, cas_mask);
        // 5. chT: [b][i][h] -> [b][h][i] (ht-hi in B0 dead)
        trans_bf_k<<<dim3(HD / 32, SLEN / 32, BSZ), blk, 0, stream>>>(
            chH, chL, chTH, chTL, SLEN, HD);
        // 6. dep[b] = score_b @ ch_b -> d_out hi/lo (ht-lo dead)
        mgemm<0, 0, 0, 0, 1, 0, 0><<<dim3(8, 4, 32), blk, 0, stream>>>(
            scB, scB + 512, 1024, SLEN * 1024, chTH, chTL, SLEN, HD * SLEN,
            nullptr, nullptr, nullptr, 0, 0,
            depH, depL, HD, SLEN * HD, SLEN, HD, SLEN, nofp, nofp, nofpm);
        // weight splits phase 2 (scores dead)
        tsplit_k<<<dim3(HD / 32, 2048 / 32), blk, 0, stream>>>(Wg, Wgh, Wgl, 2048, HD);
        tsplit_k<<<dim3(HD / 32, HD / 32), blk, 0, stream>>>(Wm1, Wm1h, Wm1l, HD, HD);
        split_k<<<dim3(1024), blk, 0, stream>>>(time_weight, twH, twL, MR * DTW / 4);
        tsplit_k<<<dim3(HD / 32, DTW / 32), blk, 0, stream>>>(Wti, WtiTh, WtiTl, DTW, HD);
        // 7. gate_pre = ch@WgTop + bg -> B0 fp32 (chT dead)
        mgemm<0, 0, 0, 1, 0, 1, 0><<<dim3(8, 128, 1), blk, 0, stream>>>(
            chH, chL, HD, 0, Wgh, Wgl, 2048, 0, bg, nullptr,
            gp, HD, 0, nullptr, nullptr, 0, 0, (int)MR, HD, HD, nofp, nofp, nofpm);
        // 8. gate2 + encode fused: enc=(sig(gp+dep@WgBot)*ch + (1-sig)*dep)*mask
        //    A = dep (also read in epilogue), C = gp (read), OH/OL = ch -> enc.
        mgemm<0, 0, 0, 0, 0, 1, 2><<<dim3(8, 128, 1), blk, 0, stream>>>(
            depH, depL, HD, 0, Wgh + 1024, Wgl + 1024, 2048, 0, nullptr, cas_mask,
            gp, HD, 0, chH, chL, HD, 0, (int)MR, HD, HD, nofp, nofp, nofpm);
        // 9. tinf = elu(tw@WtiT + bti) -> d_out fp32 (dep dead), MFMA K=64
        mgemm<1, 0, 0, 1, 0, 1, 0><<<dim3(8, 128, 1), blk, 0, stream>>>(
            twH, twL, DTW, 0, WtiTh, WtiTl, DTW, 0, bti, nullptr,
            tinf, HD, 0, nullptr, nullptr, 0, 0, (int)MR, HD, DTW, nofp, nofp, nofpm);
        // 10. m2[r] = sum_h elu(enc@Wm1+bm1)[r,h]*tinf[r,h]*Wm2[h] (bm2 dropped:
        //     pool softmax is shift-invariant)
        zero_k<<<dim3(64), blk, 0, stream>>>(m2, MR);
        mgemm<0, 0, 0, 0, 0, 1, 1><<<dim3(8, 128, 1), blk, 0, stream>>>(
            chH, chL, HD, 0, Wm1h, Wm1l, HD, 0, bm1, nullptr,
            nullptr, 0, 0, nullptr, nullptr, 0, 0, (int)MR, HD, HD,
            tinf, Wm2, m2);
        // 11-12.
        pool_softmax_k<<<dim3(BSZ), blk, 0, stream>>>(m2, cas_mask, av);
        final_bf_k<<<dim3(8192), blk, 0, stream>>>(chH, chL, av, out, NH / 4);
    } else {
        // ---- fp32 fallback (round-1 proven path) ----
        float* S0 = B0;
        float* S1 = B1;
        float* S3 = B2;
        dim3 gBig(HD / BN, (int)(MR / BM), 1);
        gemm_k<0, 1, 0, 1><<<gBig, blk, 0, stream>>>(cas_emb, 0, W1, 0, b1, cas_mask, S0, 0, (int)MR, HD, DEMB);
        gemm_k<0, 0, 0, 0><<<gBig, blk, 0, stream>>>(S0, 0, Wh, 0, bh, nullptr, S1, 0, (int)MR, HD, HD);
        gemm_k<0, 0, 0, 0><<<gBig, blk, 0, stream>>>(S0, 0, Wt, 0, bt, nullptr, out, 0, (int)MR, HD, HD);
        gemm_k<1, 0, 0, 0><<<dim3(SLEN / BN, SLEN / BM, BSZ), blk, 0, stream>>>(
            S1, (long long)SLEN * HD, out, (long long)SLEN * HD, nullptr, nullptr,
            S3, (long long)SLEN * SLEN, SLEN, SLEN, HD);
        attn_softmax_k<<<dim3(BSZ * SLEN), blk, 0, stream>>>(S3, cas_mask);
        gemm_k<0, 0, 0, 0><<<dim3(HD / BN, SLEN / BM, BSZ), blk, 0, stream>>>(
            S3, (long long)SLEN * SLEN, S0, (long long)SLEN * HD, nullptr, nullptr,
            out, (long long)SLEN * HD, SLEN, HD, SLEN);
        gemm_k<0, 0, 0, 0><<<gBig, blk, 0, stream>>>(S0, 0, Wg, 0, bg, nullptr, S1, 0, (int)MR, HD, HD);
        gemm_k<0, 0, 1, 0><<<gBig, blk, 0, stream>>>(out, 0, Wg + (long long)HD * HD, 0, nullptr, nullptr, S1, 0, (int)MR, HD, HD);
        long long n4 = NH / 4;
        encode_k<<<dim3(8192), blk, 0, stream>>>(S1, S0, out, cas_mask, n4);
        gemm_k<0, 1, 0, 0><<<gBig, blk, 0, stream>>>(S0, 0, Wm1, 0, bm1, nullptr, S1, 0, (int)MR, HD, HD);
        gemm_k<0, 1, 0, 0><<<gBig, blk, 0, stream>>>(time_weight, 0, Wti, 0, bti, nullptr, out, 0, (int)MR, HD, DTW);
        map2_k<<<dim3((int)MR), blk, 0, stream>>>(S1, out, Wm2, bm2, m2);
        pool_softmax_k<<<dim3(BSZ), blk, 0, stream>>>(m2, cas_mask, av);
        final_k<<<dim3(8192), blk, 0, stream>>>(S0, av, out, n4);
    }
}